// Round 8
// baseline (176.851 us; speedup 1.0000x reference)
//
#include <hip/hip_runtime.h>

typedef __attribute__((ext_vector_type(8))) short bf16x8;
typedef __attribute__((ext_vector_type(16))) float f32x16;
typedef __attribute__((ext_vector_type(4))) float f32x4;

#define NPTS 32
#define HID 256
#define FANIN 260
#define NKB 17          // 16 h K-blocks (K=16 each) + 1 x/bias block
#define OUTSTRIDE 8192  // NPTS*HID

__device__ __forceinline__ unsigned short f2bf(float f) {
  unsigned u = __builtin_bit_cast(unsigned, f);
  u += 0x7fffu + ((u >> 16) & 1u);  // round-to-nearest-even
  return (unsigned short)(u >> 16);
}

// prep (validated): coalesced. grid = 32 p * 8 nb; block 256.
// pack[((p*8 + nb)*17 + kb)*64 + lane], (m = lane&31, g = lane>>5):
//   kb<16:  frag[i] = W[p][nb*32 + m][kb*16 + g*8 + i]
//   kb==16: g==0 -> {W[p][m][256..260), bias[p][m], 0,0,0}; g==1 -> 0
__global__ __launch_bounds__(256) void prep_kernel(
    const float* __restrict__ W, const float* __restrict__ bias,
    bf16x8* __restrict__ pack) {
  __shared__ float wl[32 * FANIN];  // 33.3 KB
  const int p = blockIdx.x >> 3;
  const int nb = blockIdx.x & 7;
  const int t = threadIdx.x;
  const f32x4* src = reinterpret_cast<const f32x4*>(
      W + ((size_t)p * HID + nb * 32) * FANIN);
  for (int i = t; i < 32 * FANIN / 4; i += 256)  // 260%4==0: never crosses rows
    *reinterpret_cast<f32x4*>(wl + i * 4) = src[i];
  __syncthreads();
  const int lane = t & 63;
  const int wv = t >> 6;
  const int m = lane & 31;
  const int g = lane >> 5;
  const float* rowp = wl + m * FANIN;
  for (int kb = wv; kb < NKB; kb += 4) {
    unsigned short e[8];
#pragma unroll
    for (int i = 0; i < 8; ++i) e[i] = 0;
    if (kb < 16) {
      int k0 = kb * 16 + g * 8;
#pragma unroll
      for (int i = 0; i < 8; ++i) e[i] = f2bf(rowp[k0 + i]);
    } else if (g == 0) {
      e[0] = f2bf(rowp[256]);
      e[1] = f2bf(rowp[257]);
      e[2] = f2bf(rowp[258]);
      e[3] = f2bf(rowp[259]);
      e[4] = f2bf(bias[p * HID + nb * 32 + m]);
    }
    bf16x8 v;
#pragma unroll
    for (int i = 0; i < 8; ++i) v[i] = (short)e[i];
    pack[(((size_t)p * 8 + nb) * NKB + kb) * 64 + lane] = v;
  }
}

// enc v8: K-split wave specialization. 1024 thr = 16 waves = 4 waves/SIMD.
// Wave (t = wv&7, half = wv>>3) computes tile t (hidden cols t*32..t*32+32)
// over kb = half*8..half*8+8 (half1 also does x/bias). Partial accs exchanged
// via swizzled LDS stage; each wave epilogues 8 rows. W bytes/CU/step
// unchanged vs v2 (halves read disjoint kb), per-wave VGPR ~100 (cap 128).
// LDS: h dbuf 2x16KB @[0,32K); stage 32KB @[32K,64K). 2 lgkm-only barriers
// per step; stores never drained in-loop.
__global__ __launch_bounds__(1024, 4) void enc_kernel(
    const float* __restrict__ path, const bf16x8* __restrict__ pack,
    float* __restrict__ out) {
  __shared__ __align__(16) char lds[65536];
  const int tid = threadIdx.x;
  const int lane = tid & 63;
  const int wv = tid >> 6;    // 0..15
  const int t = wv & 7;       // hidden tile
  const int half = wv >> 3;   // K half
  const int col = lane & 31;  // A-row (batch) / D-col (hidden)
  const int g = lane >> 5;
  const int b0 = blockIdx.x * 32;
  const int swz = col << 4;          // h-read swizzle
  const int sswz = (col & 7) << 4;   // stage swizzle

  {  // zero h buffer 0 (h0 = 0): 1024 thr x 16B = 16KB
    f32x4 z = {0.0f, 0.0f, 0.0f, 0.0f};
    *reinterpret_cast<f32x4*>(lds + tid * 16) = z;
  }

  const float4* prow =
      reinterpret_cast<const float4*>(path + (size_t)(b0 + col) * 128);
  float* outbase = out + (size_t)b0 * OUTSTRIDE + t * 32 + col;

  // BC[i] = pack frag kb = half*8 + i (i<8); BC[8] (half1 only) = kb16 x/bias
  bf16x8 BC[9];
  {
    const bf16x8* Bp0 = pack + ((size_t)t * NKB + half * 8) * 64 + lane;
#pragma unroll
    for (int i = 0; i < 8; ++i) BC[i] = Bp0[i * 64];
    if (half) BC[8] = *(pack + ((size_t)t * NKB + 16) * 64 + lane);
  }
  float4 px = prow[0];
  __syncthreads();

  for (int p = 0; p < NPTS; ++p) {
    const int pn = (p + 1 < NPTS) ? p + 1 : 0;  // clamp: harmless re-read
    const bf16x8* Bnp =
        pack + (((size_t)(pn * 8 + t)) * NKB + half * 8) * 64 + lane;
    const char* hb = lds + (p & 1) * 16384;

    f32x16 acc;
#pragma unroll
    for (int i = 0; i < 16; ++i) acc[i] = 0.0f;

#pragma unroll
    for (int i = 0; i < 8; ++i) {
      const int kbg = half * 8 + i;
      bf16x8 a = *reinterpret_cast<const bf16x8*>(
          hb + col * 512 + ((kbg * 32 + g * 16) ^ swz));
      acc = __builtin_amdgcn_mfma_f32_32x32x16_bf16(a, BC[i], acc, 0, 0, 0);
      BC[i] = Bnp[i * 64];  // prefetch step p+1
    }
    if (half) {
      bf16x8 ax;  // x/bias A-frag: g==0 lanes hold [x0..x3, 1.0, 0,0,0]
#pragma unroll
      for (int i = 0; i < 8; ++i) ax[i] = 0;
      if (g == 0) {
        ax[0] = (short)f2bf(px.x);
        ax[1] = (short)f2bf(px.y);
        ax[2] = (short)f2bf(px.z);
        ax[3] = (short)f2bf(px.w);
        ax[4] = (short)0x3F80;  // 1.0 pairs with bias row in B
      }
      acc = __builtin_amdgcn_mfma_f32_32x32x16_bf16(ax, BC[8], acc, 0, 0, 0);
      BC[8] = *(pack + (((size_t)(pn * 8 + t)) * NKB + 16) * 64 + lane);
    }
    px = prow[pn];

    // ---- stage exchange: write my OTHER 8 regs, read partner's ----
    // stage[t]: [col][row] f32, byte = t*4096 + col*128 + row*4, ^sswz
    char* stg = lds + 32768 + t * 4096 + col * 128;
    const int wrow = (half ^ 1) * 16 + 4 * g;  // rows I write: wrow..+3, +8
    {
      const int wr = (half ^ 1) * 8;  // regs I send
      f32x4 v0 = {acc[wr], acc[wr + 1], acc[wr + 2], acc[wr + 3]};
      f32x4 v1 = {acc[wr + 4], acc[wr + 5], acc[wr + 6], acc[wr + 7]};
      *reinterpret_cast<f32x4*>(stg + ((wrow * 4) ^ sswz)) = v0;
      *reinterpret_cast<f32x4*>(stg + (((wrow + 8) * 4) ^ sswz)) = v1;
    }
    asm volatile("s_waitcnt lgkmcnt(0)" ::: "memory");
    __builtin_amdgcn_s_barrier();

    const int rrow = half * 16 + 4 * g;  // rows I keep (partner wrote them)
    f32x4 u0 = *reinterpret_cast<const f32x4*>(stg + ((rrow * 4) ^ sswz));
    f32x4 u1 =
        *reinterpret_cast<const f32x4*>(stg + (((rrow + 8) * 4) ^ sswz));

    // ---- epilogue: 8 final rows ----
    char* hn = lds + ((p + 1) & 1) * 16384;
    float* outp = outbase + p * 256;
    const int kr = half * 8;  // regs I keep
#pragma unroll
    for (int j = 0; j < 8; ++j) {
      const int rr = half * 16 + (j & 3) + 8 * (j >> 2) + 4 * g;
      float part = (j < 4) ? u0[j & 3] : u1[j & 3];
      float v = fmaxf(acc[kr + j] + part, 0.0f);
      __builtin_nontemporal_store(v, outp + (size_t)rr * OUTSTRIDE);
      *reinterpret_cast<unsigned short*>(
          hn + rr * 512 + (((t * 32 + col) * 2) ^ (rr << 4))) = f2bf(v);
    }
    asm volatile("s_waitcnt lgkmcnt(0)" ::: "memory");
    __builtin_amdgcn_s_barrier();
  }
}

extern "C" void kernel_launch(void* const* d_in, const int* in_sizes, int n_in,
                              void* d_out, int out_size, void* d_ws,
                              size_t ws_size, hipStream_t stream) {
  const float* path = (const float*)d_in[0];  // [8192][128]
  const float* W = (const float*)d_in[1];     // [32][256][260]
  const float* bias = (const float*)d_in[2];  // [32][256]
  float* out = (float*)d_out;                 // [8192][8192]
  bf16x8* pack = (bf16x8*)d_ws;               // 32*8*17*64 frags = 4.45 MB

  prep_kernel<<<256, 256, 0, stream>>>(W, bias, pack);
  enc_kernel<<<256, 1024, 0, stream>>>(path, pack, out);
}

// Round 9
// 130.894 us; speedup vs baseline: 1.3511x; 1.3511x over previous
//
#include <hip/hip_runtime.h>

typedef __attribute__((ext_vector_type(8))) short bf16x8;
typedef __attribute__((ext_vector_type(16))) float f32x16;
typedef __attribute__((ext_vector_type(4))) float f32x4;

#define NPTS 32
#define HID 256
#define FANIN 260
#define NKB 17          // 16 h K-blocks (K=16 each) + 1 x/bias block
#define OUTSTRIDE 8192  // NPTS*HID

__device__ __forceinline__ unsigned short f2bf(float f) {
  unsigned u = __builtin_bit_cast(unsigned, f);
  u += 0x7fffu + ((u >> 16) & 1u);  // round-to-nearest-even
  return (unsigned short)(u >> 16);
}

// prep (validated): coalesced. grid = 32 p * 8 nb; block 256.
// pack[((p*8 + nb)*17 + kb)*64 + lane], (m = lane&31, g = lane>>5):
//   kb<16:  frag[i] = W[p][nb*32 + m][kb*16 + g*8 + i]
//   kb==16: g==0 -> {W[p][m][256..260), bias[p][m], 0,0,0}; g==1 -> 0
__global__ __launch_bounds__(256) void prep_kernel(
    const float* __restrict__ W, const float* __restrict__ bias,
    bf16x8* __restrict__ pack) {
  __shared__ float wl[32 * FANIN];  // 33.3 KB
  const int p = blockIdx.x >> 3;
  const int nb = blockIdx.x & 7;
  const int t = threadIdx.x;
  const f32x4* src = reinterpret_cast<const f32x4*>(
      W + ((size_t)p * HID + nb * 32) * FANIN);
  for (int i = t; i < 32 * FANIN / 4; i += 256)  // 260%4==0: never crosses rows
    *reinterpret_cast<f32x4*>(wl + i * 4) = src[i];
  __syncthreads();
  const int lane = t & 63;
  const int wv = t >> 6;
  const int m = lane & 31;
  const int g = lane >> 5;
  const float* rowp = wl + m * FANIN;
  for (int kb = wv; kb < NKB; kb += 4) {
    unsigned short e[8];
#pragma unroll
    for (int i = 0; i < 8; ++i) e[i] = 0;
    if (kb < 16) {
      int k0 = kb * 16 + g * 8;
#pragma unroll
      for (int i = 0; i < 8; ++i) e[i] = f2bf(rowp[k0 + i]);
    } else if (g == 0) {
      e[0] = f2bf(rowp[256]);
      e[1] = f2bf(rowp[257]);
      e[2] = f2bf(rowp[258]);
      e[3] = f2bf(rowp[259]);
      e[4] = f2bf(bias[p * HID + nb * 32 + m]);
    }
    bf16x8 v;
#pragma unroll
    for (int i = 0; i < 8; ++i) v[i] = (short)e[i];
    pack[(((size_t)p * 8 + nb) * NKB + kb) * 64 + lane] = v;
  }
}

// enc v9: R2 structure + M=64 register blocking. Grid 128 blocks x 64 batch
// rows. Each wave holds ONE BC[17] W-fragment set and runs TWO 32-row
// A-subtiles against it (acc0/acc1, interleaved chains) -> W L2 traffic
// per output byte HALVES (4.45 -> 2.23 MB/step/XCD). Store/epilogue/barrier
// structure identical to R2 (proven 93.5): scalar NT stores + h ds_writes
// interleaved, lgkm-only wait, raw barrier, rolling BC/px prefetch.
// VGPR ~150 (BC 68 + acc 32 + frags + ptrs) under (512,2) cap 256.
// LDS: h bf16 [64][256] double-buffered = 2x32KB.
__global__ __launch_bounds__(512, 2) void enc_kernel(
    const float* __restrict__ path, const bf16x8* __restrict__ pack,
    float* __restrict__ out) {
  __shared__ __align__(16) char lds[65536];
  const int tid = threadIdx.x;
  const int lane = tid & 63;
  const int w = tid >> 6;     // wave id 0..7 = hidden col-block
  const int col = lane & 31;  // A-row within subtile / D-col
  const int g = lane >> 5;    // k-group
  const int b0 = blockIdx.x * 64;
  const int swz = col << 4;   // same for row col and col+32 ((row&31)<<4)

  {  // zero h buffer 0 (h0 = 0): 512 thr x 64B = 32KB
    f32x4 z = {0.0f, 0.0f, 0.0f, 0.0f};
#pragma unroll
    for (int s = 0; s < 4; ++s)
      *reinterpret_cast<f32x4*>(lds + tid * 64 + s * 16) = z;
  }

  const float4* prow0 =
      reinterpret_cast<const float4*>(path + (size_t)(b0 + col) * 128);
  const float4* prow1 =
      reinterpret_cast<const float4*>(path + (size_t)(b0 + 32 + col) * 128);
  float* outbase = out + (size_t)b0 * OUTSTRIDE + w * 32 + col;

  bf16x8 BC[NKB];
  {
    const bf16x8* Bp0 = pack + (size_t)w * NKB * 64 + lane;
#pragma unroll
    for (int kb = 0; kb < NKB; ++kb) BC[kb] = Bp0[kb * 64];
  }
  float4 px0 = prow0[0];
  float4 px1 = prow1[0];
  __syncthreads();

  for (int p = 0; p < NPTS; ++p) {
    const int pn = (p + 1 < NPTS) ? p + 1 : 0;  // clamp: harmless re-read
    const bf16x8* Bnp = pack + ((size_t)(pn * 8 + w) * NKB) * 64 + lane;
    const char* hb = lds + (p & 1) * 32768;

    f32x16 acc0, acc1;  // subtile 0 (rows 0-31), subtile 1 (rows 32-63)
#pragma unroll
    for (int i = 0; i < 16; ++i) {
      acc0[i] = 0.0f;
      acc1[i] = 0.0f;
    }

#pragma unroll
    for (int kb = 0; kb < 16; ++kb) {
      const int off = (kb * 32 + g * 16) ^ swz;
      bf16x8 a0 = *reinterpret_cast<const bf16x8*>(hb + col * 512 + off);
      bf16x8 a1 =
          *reinterpret_cast<const bf16x8*>(hb + (col + 32) * 512 + off);
      acc0 = __builtin_amdgcn_mfma_f32_32x32x16_bf16(a0, BC[kb], acc0, 0, 0, 0);
      acc1 = __builtin_amdgcn_mfma_f32_32x32x16_bf16(a1, BC[kb], acc1, 0, 0, 0);
      BC[kb] = Bnp[kb * 64];  // rolling prefetch for step p+1
    }
    {
      bf16x8 ax0, ax1;  // x/bias A-frags: g==0 lanes hold [x0..x3, 1.0, 0..]
#pragma unroll
      for (int i = 0; i < 8; ++i) {
        ax0[i] = 0;
        ax1[i] = 0;
      }
      if (g == 0) {
        ax0[0] = (short)f2bf(px0.x);
        ax0[1] = (short)f2bf(px0.y);
        ax0[2] = (short)f2bf(px0.z);
        ax0[3] = (short)f2bf(px0.w);
        ax0[4] = (short)0x3F80;  // 1.0 pairs with bias row in B
        ax1[0] = (short)f2bf(px1.x);
        ax1[1] = (short)f2bf(px1.y);
        ax1[2] = (short)f2bf(px1.z);
        ax1[3] = (short)f2bf(px1.w);
        ax1[4] = (short)0x3F80;
      }
      acc0 = __builtin_amdgcn_mfma_f32_32x32x16_bf16(ax0, BC[16], acc0, 0, 0, 0);
      acc1 = __builtin_amdgcn_mfma_f32_32x32x16_bf16(ax1, BC[16], acc1, 0, 0, 0);
      BC[16] = Bnp[16 * 64];
    }
    px0 = prow0[pn];
    px1 = prow1[pn];

    // epilogue (R2 interleave): per row, h ds_write + NT out store
    char* hn = lds + ((p + 1) & 1) * 32768;
    float* outp = outbase + p * 256;
#pragma unroll
    for (int ms = 0; ms < 2; ++ms) {
#pragma unroll
      for (int r = 0; r < 16; ++r) {
        const int rr = (r & 3) + 8 * (r >> 2) + 4 * g;  // C/D row in subtile
        const int row = ms * 32 + rr;                   // batch row in block
        float v = fmaxf((ms ? acc1[r] : acc0[r]), 0.0f);
        *reinterpret_cast<unsigned short*>(
            hn + row * 512 + (((w * 32 + col) * 2) ^ (rr << 4))) = f2bf(v);
        __builtin_nontemporal_store(v, outp + (size_t)row * OUTSTRIDE);
      }
    }
    asm volatile("s_waitcnt lgkmcnt(0)" ::: "memory");
    __builtin_amdgcn_s_barrier();
  }
}

extern "C" void kernel_launch(void* const* d_in, const int* in_sizes, int n_in,
                              void* d_out, int out_size, void* d_ws,
                              size_t ws_size, hipStream_t stream) {
  const float* path = (const float*)d_in[0];  // [8192][128]
  const float* W = (const float*)d_in[1];     // [32][256][260]
  const float* bias = (const float*)d_in[2];  // [32][256]
  float* out = (float*)d_out;                 // [8192][8192]
  bf16x8* pack = (bf16x8*)d_ws;               // 32*8*17*64 frags = 4.45 MB

  prep_kernel<<<256, 256, 0, stream>>>(W, bias, pack);
  enc_kernel<<<128, 512, 0, stream>>>(path, pack, out);
}

// Round 10
// 95.881 us; speedup vs baseline: 1.8445x; 1.3652x over previous
//
#include <hip/hip_runtime.h>

typedef __attribute__((ext_vector_type(8))) short bf16x8;
typedef __attribute__((ext_vector_type(16))) float f32x16;
typedef __attribute__((ext_vector_type(4))) float f32x4;

#define NPTS 32
#define HID 256
#define FANIN 260
#define NKB 17          // 16 h K-blocks (K=16 each) + 1 x/bias block
#define OUTSTRIDE 8192  // NPTS*HID

__device__ __forceinline__ unsigned short f2bf(float f) {
  unsigned u = __builtin_bit_cast(unsigned, f);
  u += 0x7fffu + ((u >> 16) & 1u);  // round-to-nearest-even
  return (unsigned short)(u >> 16);
}

// prep v3 (validated R4/R6): coalesced. grid = 32 p * 8 nb; block 256.
// pack[((p*8 + nb)*17 + kb)*64 + lane], (m = lane&31, g = lane>>5):
//   kb<16:  frag[i] = W[p][nb*32 + m][kb*16 + g*8 + i]
//   kb==16: g==0 -> {W[p][m][256..260), bias[p][m], 0,0,0}; g==1 -> 0
__global__ __launch_bounds__(256) void prep_kernel(
    const float* __restrict__ W, const float* __restrict__ bias,
    bf16x8* __restrict__ pack) {
  __shared__ float wl[32 * FANIN];  // 33.3 KB
  const int p = blockIdx.x >> 3;
  const int nb = blockIdx.x & 7;
  const int t = threadIdx.x;
  const f32x4* src = reinterpret_cast<const f32x4*>(
      W + ((size_t)p * HID + nb * 32) * FANIN);
  for (int i = t; i < 32 * FANIN / 4; i += 256)  // 260%4==0: never crosses rows
    *reinterpret_cast<f32x4*>(wl + i * 4) = src[i];
  __syncthreads();
  const int lane = t & 63;
  const int wv = t >> 6;
  const int m = lane & 31;
  const int g = lane >> 5;
  const float* rowp = wl + m * FANIN;
  for (int kb = wv; kb < NKB; kb += 4) {
    unsigned short e[8];
#pragma unroll
    for (int i = 0; i < 8; ++i) e[i] = 0;
    if (kb < 16) {
      int k0 = kb * 16 + g * 8;
#pragma unroll
      for (int i = 0; i < 8; ++i) e[i] = f2bf(rowp[k0 + i]);
    } else if (g == 0) {
      e[0] = f2bf(rowp[256]);
      e[1] = f2bf(rowp[257]);
      e[2] = f2bf(rowp[258]);
      e[3] = f2bf(rowp[259]);
      e[4] = f2bf(bias[p * HID + nb * 32 + m]);
    }
    bf16x8 v;
#pragma unroll
    for (int i = 0; i < 8; ++i) v[i] = (short)e[i];
    pack[(((size_t)p * 8 + nb) * NKB + kb) * 64 + lane] = v;
  }
}

// enc v10: EXACT 93.5us structure (R1 macro: reg-dbuf BA/BB, NT scalar
// stores, lgkm-only barrier, (512,2)) + per-block tile rotation
// t = (w + blockIdx.x) & 7. All 32 same-XCD blocks previously read the
// IDENTICAL pack address stream in identical order -> same-address bursts
// serialize on one L2 slice (no multicast). Rotation spreads concurrent
// blocks across the 8 disjoint 17.4KB tile regions of each step's W chunk.
__global__ __launch_bounds__(512, 2) void enc_kernel(
    const float* __restrict__ path, const bf16x8* __restrict__ pack,
    float* __restrict__ out) {
  __shared__ __align__(16) char lds[32768];
  const int tid = threadIdx.x;
  const int lane = tid & 63;
  const int w = tid >> 6;                       // wave id
  const int t = (w + (int)blockIdx.x) & 7;      // rotated hidden tile
  const int col = lane & 31;                    // A-row / B-col / C-col
  const int g = lane >> 5;                      // k-group
  const int b0 = blockIdx.x * 32;

  // zero h buffer 0 (h0 = 0)
  {
    f32x4 z = {0.0f, 0.0f, 0.0f, 0.0f};
    *reinterpret_cast<f32x4*>(lds + tid * 32) = z;
    *reinterpret_cast<f32x4*>(lds + tid * 32 + 16) = z;
  }

  const float4* prow =
      reinterpret_cast<const float4*>(path + (size_t)(b0 + col) * 128);
  float* outbase = out + (size_t)b0 * OUTSTRIDE;
  const int swz = col << 4;
  int cur = 0;

  bf16x8 BA[NKB], BB[NKB];
  float4 pxA, pxB;
  {
    const bf16x8* Bp0 = pack + (size_t)t * NKB * 64 + lane;
#pragma unroll
    for (int kb = 0; kb < NKB; ++kb) BA[kb] = Bp0[kb * 64];
    pxA = prow[0];
  }
  __syncthreads();

#define STEP(P, BC, BN, PX, PXN, PNEXT)                                       \
  {                                                                           \
    const int p_ = (P);                                                       \
    const bf16x8* Bnp =                                                       \
        pack + ((size_t)((PNEXT) * 8 + t) * NKB) * 64 + lane;                 \
    f32x16 acc0, acc1;                                                        \
    _Pragma("unroll") for (int i = 0; i < 16; ++i) {                          \
      acc0[i] = 0.0f;                                                         \
      acc1[i] = 0.0f;                                                         \
    }                                                                         \
    bf16x8 ax;                                                                \
    _Pragma("unroll") for (int i = 0; i < 8; ++i) ax[i] = 0;                  \
    if (g == 0) {                                                             \
      ax[0] = (short)f2bf((PX).x);                                            \
      ax[1] = (short)f2bf((PX).y);                                            \
      ax[2] = (short)f2bf((PX).z);                                            \
      ax[3] = (short)f2bf((PX).w);                                            \
      ax[4] = (short)0x3F80; /* 1.0 pairs with bias row in B */               \
    }                                                                         \
    const char* hb = lds + cur * 16384;                                       \
    _Pragma("unroll") for (int kb = 0; kb < 16; ++kb) {                       \
      bf16x8 a = *reinterpret_cast<const bf16x8*>(                            \
          hb + col * 512 + ((kb * 32 + g * 16) ^ swz));                       \
      if (kb & 1)                                                             \
        acc1 = __builtin_amdgcn_mfma_f32_32x32x16_bf16(a, (BC)[kb], acc1,     \
                                                       0, 0, 0);              \
      else                                                                    \
        acc0 = __builtin_amdgcn_mfma_f32_32x32x16_bf16(a, (BC)[kb], acc0,     \
                                                       0, 0, 0);              \
      (BN)[kb] = Bnp[kb * 64]; /* prefetch: before this step's stores */      \
    }                                                                         \
    acc0 = __builtin_amdgcn_mfma_f32_32x32x16_bf16(ax, (BC)[16], acc0,        \
                                                   0, 0, 0);                  \
    (BN)[16] = Bnp[16 * 64];                                                  \
    (PXN) = prow[(PNEXT)];                                                    \
    char* hn = lds + (cur ^ 1) * 16384;                                       \
    float* outp = outbase + p_ * 256 + t * 32 + col;                          \
    _Pragma("unroll") for (int r = 0; r < 16; ++r) {                          \
      int rr = (r & 3) + 8 * (r >> 2) + 4 * g; /* C/D row (verified) */       \
      float v = fmaxf(acc0[r] + acc1[r], 0.0f);                               \
      __builtin_nontemporal_store(v, outp + (size_t)rr * OUTSTRIDE);          \
      *reinterpret_cast<unsigned short*>(                                     \
          hn + rr * 512 + (((t * 32 + col) * 2) ^ (rr << 4))) = f2bf(v);      \
    }                                                                         \
    asm volatile("s_waitcnt lgkmcnt(0)" ::: "memory");                        \
    __builtin_amdgcn_s_barrier();                                             \
    cur ^= 1;                                                                 \
  }

  for (int p = 0; p < NPTS; p += 2) {
    const int pn2 = (p + 2 < NPTS) ? (p + 2) : 0;  // clamp: harmless re-read
    STEP(p, BA, BB, pxA, pxB, (p + 1));
    STEP((p + 1), BB, BA, pxB, pxA, pn2);
  }
#undef STEP
}

extern "C" void kernel_launch(void* const* d_in, const int* in_sizes, int n_in,
                              void* d_out, int out_size, void* d_ws,
                              size_t ws_size, hipStream_t stream) {
  const float* path = (const float*)d_in[0];  // [8192][128]
  const float* W = (const float*)d_in[1];     // [32][256][260]
  const float* bias = (const float*)d_in[2];  // [32][256]
  float* out = (float*)d_out;                 // [8192][8192]
  bf16x8* pack = (bf16x8*)d_ws;               // 32*8*17*64 frags = 4.45 MB

  prep_kernel<<<256, 256, 0, stream>>>(W, bias, pack);
  enc_kernel<<<256, 512, 0, stream>>>(path, pack, out);
}